// Round 3
// baseline (720.438 us; speedup 1.0000x reference)
//
#include <hip/hip_runtime.h>

#define HID  256
#define DDYN 5
#define NS   27
#define TS   365
#define BS   4            // batch rows per block
#define NW   16           // waves per block
#define UPW  16           // hidden units owned per wave
#define NTILE 3           // 16-col MFMA tiles per wave (one per gate)
#define SA   272          // Abuf row stride in bf16 elems (256 h + 16 pad; SA/2 % 32 == 8 -> 2-way banks for 16-lane reads)
#define G3   768          // 3 gates * 256

typedef short short8 __attribute__((ext_vector_type(8)));
typedef float f32x4  __attribute__((ext_vector_type(4)));

__device__ __forceinline__ unsigned short f2bf(float f) {
    union { float f; unsigned u; } v; v.f = f;
    unsigned r = v.u + 0x7FFFu + ((v.u >> 16) & 1u);   // RNE
    return (unsigned short)(r >> 16);
}
__device__ __forceinline__ float bf2f(unsigned short s) {
    union { unsigned u; float f; } v; v.u = ((unsigned)s) << 16;
    return v.f;
}
__device__ __forceinline__ float bf2f_s(short s) {
    union { unsigned u; float f; } v; v.u = ((unsigned)(unsigned short)s) << 16;
    return v.f;
}
__device__ __forceinline__ float fsig(float x) {
    float e = __builtin_amdgcn_exp2f(-1.4426950408889634f * x);
    return __builtin_amdgcn_rcpf(1.0f + e);
}
__device__ __forceinline__ float ftanh(float x) {
    float e = __builtin_amdgcn_exp2f(2.8853900817779268f * x);
    return 1.0f - 2.0f * __builtin_amdgcn_rcpf(1.0f + e);
}

// Register discipline (R2-R6 post-mortems), the three hard rules:
//  1. Bf MUST be statically indexed -> FULL unroll of the K-chunk loop.
//     (R6: "#pragma unroll 2" made Bf[j][c] runtime-indexed -> compiler
//      demoted all 96 weight regs to scratch -> 18 GB/dispatch re-fetch.)
//  2. No x/bias MFMA in the loop: it is a rank-6 update; its transient regs
//     (b8 frag + conditional A frag + exec juggling) were R5's 202 MB spill.
//     Folded into phase B as ~20 scalar FMAs from LDS (transient regs only).
//  3. Bound A-frag prefetch depth: memory clobber after each chunk stops the
//     scheduler from hoisting all 8 ds_reads (R4/R5: +28 live regs -> spill).
// Peak live ~122 of the 128 (V+A)/wave cap at 1024 threads.
//
// R7 (re-submitted; three GPU-timeout rounds, never measured): A-frag ds_reads
// exec-masked to lanes n<4. MFMA A rows 4-15 are structurally zero (only 4
// batch rows per block); previously 48/64 lanes per wave issued ds_read_b128
// of zeros -> 128 KB/step of LDS reads, the dominant per-CU pipe. Masked:
// 32 KB/step (minimum: every wave needs all of h). Abuf shrunk to the 4 live
// rows, SA retuned 264->272 so the 16 active lanes land 2-way on banks (free)
// instead of a 4-way cluster.
__global__ __launch_bounds__(1024)
void ealstm_kernel(const float* __restrict__ x_dyn,  const float* __restrict__ x_stat,
                   const float* __restrict__ W_i,    const float* __restrict__ b_i,
                   const float* __restrict__ W_f,    const float* __restrict__ b_f,
                   const float* __restrict__ W_g,    const float* __restrict__ b_g,
                   const float* __restrict__ W_o,    const float* __restrict__ b_o,
                   const float* __restrict__ W_head, const float* __restrict__ b_head,
                   float* __restrict__ out)
{
    // LDS: 4352 + 12288 + 12288 + 23360 + 432 = 52720 B
    __shared__ __align__(16) unsigned short Abuf[2][4 * SA];  // h rows 0..3 only, double-buffered
    __shared__ __align__(16) float          pre[NW * 192];    // h-part preacts, wave-private
    __shared__ __align__(16) unsigned short WxL[G3 * 8];      // per col: Wx[0..4], bias, 0, 0 (bf16)
    __shared__ __align__(16) unsigned short xcA[TS * 4 * 8];  // per (t,row): x[0..4], 1.0, 0, 0 (bf16)
    __shared__ __align__(16) float          xst[BS * NS];

    const int tid  = threadIdx.x;
    const int bid  = blockIdx.x;
    const int b0   = bid * BS;
    const int lane = tid & 63;
    const int wv   = tid >> 6;        // wave 0..15
    const int q    = lane >> 4;       // quad 0..3 (MFMA K-group)
    const int n    = lane & 15;       // MFMA col-in-tile / A row
    const int up   = lane >> 2;       // unit-local 0..15 (phase B)
    const int r    = lane & 3;        // batch row 0..3 (phase B)
    const int u    = wv * UPW + up;   // owned hidden unit (phase B)

    // ---- init LDS ----
    for (int i = tid; i < 2 * 4 * SA / 2; i += 1024)
        ((unsigned int*)Abuf)[i] = 0u;                 // zero both A buffers (h0 = 0)
    for (int i = tid; i < BS * NS; i += 1024)
        xst[i] = x_stat[(b0 + i / NS) * NS + (i % NS)];
    for (int i = tid; i < TS * BS; i += 1024) {        // x rows, 16B-aligned per (t,row)
        int t = i >> 2, rr = i & 3;
        const float* xp = x_dyn + ((size_t)(b0 + rr) * TS + t) * DDYN;
        unsigned short* dst = &xcA[(unsigned)i * 8];
        #pragma unroll
        for (int d = 0; d < DDYN; d++) dst[d] = f2bf(xp[d]);
        dst[5] = 0x3F80; dst[6] = 0; dst[7] = 0;
    }
    if (tid < G3) {
        int col = tid;
        int gate = col >> 8, hc = col & 255;
        const float* Wg = gate == 0 ? W_f : (gate == 1 ? W_g : W_o);
        const float* bg = gate == 0 ? b_f : (gate == 1 ? b_g : b_o);
        #pragma unroll
        for (int d = 0; d < DDYN; d++) WxL[col * 8 + d] = f2bf(Wg[hc * (DDYN + HID) + d]);
        WxL[col * 8 + 5] = f2bf(bg[hc]);
        WxL[col * 8 + 6] = 0; WxL[col * 8 + 7] = 0;
    }

    // ---- persistent B fragments: 3 tiles x 8 K-chunks x 4 VGPR = 96 regs ----
    short8 Bf[NTILE][8];
    #pragma unroll
    for (int j = 0; j < NTILE; j++) {
        int urow = wv * UPW + n;           // weight row (hidden unit), gate j
        const float* Wg = j == 0 ? W_f : (j == 1 ? W_g : W_o);
        const float* wrow = Wg + urow * (DDYN + HID) + DDYN;   // skip x-part
        #pragma unroll
        for (int c = 0; c < 8; c++) {
            int k0 = c * 32 + q * 8;
            short8 fr;
            #pragma unroll
            for (int e = 0; e < 8; e++) fr[e] = (short)f2bf(wrow[k0 + e]);
            Bf[j][c] = fr;
        }
    }
    __syncthreads();

    // ---- i_gate for this thread's (unit u, row r) ----
    float ig, cst = 0.f;
    {
        float a = b_i[u];
        for (int s = 0; s < NS; s++)
            a += xst[r * NS + s] * W_i[u * NS + s];
        ig = fsig(a);
    }
    __syncthreads();

    const int  aoff  = n * SA;
    const bool ardr  = (n < 4);           // only A rows 0..3 exist; others are zero
    const int  pbase = wv * 192 + lane;   // phase-B read base (gate 0)

    // ---- time loop: ONE barrier per step ----
    for (int t = 0; t < TS; t++) {
        const unsigned short* __restrict__ pA = Abuf[t & 1];
        unsigned short*       __restrict__ pB = Abuf[(t + 1) & 1];

        // Phase A: h-part preacts (8 K-chunks, FULLY unrolled -> Bf static).
        f32x4 acc[NTILE];
        #pragma unroll
        for (int j = 0; j < NTILE; j++) acc[j] = (f32x4){0.f, 0.f, 0.f, 0.f};
        #pragma unroll
        for (int c = 0; c < 8; c++) {
            short8 a = (short8){0, 0, 0, 0, 0, 0, 0, 0};
            if (ardr)                                   // exec-masked: 16/64 lanes hit LDS
                a = *(const short8*)&pA[aoff + c * 32 + q * 8];
            #pragma unroll
            for (int j = 0; j < NTILE; j++)
                acc[j] = __builtin_amdgcn_mfma_f32_16x16x32_bf16(a, Bf[j][c], acc[j], 0, 0, 0);
            // clobber: next chunk's ds_read may not hoist above this point ->
            // at most ~2 A-frags live instead of 8 (R4/R5 spill source).
            __asm__ volatile("" ::: "memory");
        }
        if (q == 0) {   // lanes 0..15 hold rows 0..3 of col n -> wave-private pre region
            #pragma unroll
            for (int j = 0; j < NTILE; j++)
                *(f32x4*)&pre[wv * 192 + j * 64 + n * 4] = acc[j];
        }
        // intra-wave exchange: wave's own writes -> wave's own reads
        __asm__ volatile("s_waitcnt lgkmcnt(0)" ::: "memory");

        // Phase B: LSTM cell for (unit u, row r); x·Wx + bias folded in here
        {
            short8 xv = *(const short8*)&xcA[(unsigned)(t * 4 + r) * 8];
            short8 wf = *(const short8*)&WxL[(u)        * 8];
            short8 wg = *(const short8*)&WxL[(256 + u)  * 8];
            short8 wo = *(const short8*)&WxL[(512 + u)  * 8];
            float pf = pre[pbase]       + bf2f_s(wf[5]);
            float pg = pre[pbase + 64]  + bf2f_s(wg[5]);
            float po = pre[pbase + 128] + bf2f_s(wo[5]);
            #pragma unroll
            for (int d = 0; d < DDYN; d++) {
                float xd = bf2f_s(xv[d]);
                pf += xd * bf2f_s(wf[d]);
                pg += xd * bf2f_s(wg[d]);
                po += xd * bf2f_s(wo[d]);
            }
            float f  = fsig(pf);
            float g_ = ftanh(pg);
            float o  = fsig(po);
            cst = f * cst + ig * g_;
            float h = o * ftanh(cst);
            pB[r * SA + u] = f2bf(h);
        }
        __syncthreads();
    }

    // ---- head: out[b] = h . W_head + b_head (TS odd -> final h in buffer 1) ----
    {
        float h = bf2f(Abuf[1][r * SA + u]);
        pre[u * 4 + r] = h * W_head[u];
    }
    __syncthreads();
    if (tid < 64) {
        f32x4 s = *(const f32x4*)&pre[tid * 4];
        #pragma unroll
        for (int k = 1; k < 4; k++) {
            f32x4 v = *(const f32x4*)&pre[(tid + k * 64) * 4];
            #pragma unroll
            for (int rr = 0; rr < BS; rr++) s[rr] += v[rr];
        }
        #pragma unroll
        for (int off = 32; off > 0; off >>= 1)
            #pragma unroll
            for (int rr = 0; rr < BS; rr++) s[rr] += __shfl_down(s[rr], off, 64);
        if (tid == 0) {
            float bh = b_head[0];
            #pragma unroll
            for (int rr = 0; rr < BS; rr++) out[b0 + rr] = s[rr] + bh;
        }
    }
}

extern "C" void kernel_launch(void* const* d_in, const int* in_sizes, int n_in,
                              void* d_out, int out_size, void* d_ws, size_t ws_size,
                              hipStream_t stream) {
    ealstm_kernel<<<256, 1024, 0, stream>>>(
        (const float*)d_in[0],  (const float*)d_in[1],  (const float*)d_in[2],
        (const float*)d_in[3],  (const float*)d_in[4],  (const float*)d_in[5],
        (const float*)d_in[6],  (const float*)d_in[7],  (const float*)d_in[8],
        (const float*)d_in[9],  (const float*)d_in[10], (const float*)d_in[11],
        (float*)d_out);
}

// Round 6
// 615.372 us; speedup vs baseline: 1.1707x; 1.1707x over previous
//
#include <hip/hip_runtime.h>

#define HID  256
#define DDYN 5
#define NS   27
#define TS   365
#define BS   4            // batch rows per block
#define NW   16           // waves per block
#define UPW  16           // hidden units owned per wave
#define NTILE 3           // 16-col MFMA tiles per wave (one per gate)
#define AR   5            // Abuf rows: 0..3 = h batch rows, 4 = permanent zeros
#define SA   272          // Abuf row stride in bf16 elems (8-bank shift/row; residual aliasing <=3-way, ~free)
#define G3   768          // 3 gates * 256

typedef short short8 __attribute__((ext_vector_type(8)));
typedef float f32x4  __attribute__((ext_vector_type(4)));

__device__ __forceinline__ unsigned short f2bf(float f) {
    union { float f; unsigned u; } v; v.f = f;
    unsigned r = v.u + 0x7FFFu + ((v.u >> 16) & 1u);   // RNE
    return (unsigned short)(r >> 16);
}
__device__ __forceinline__ float bf2f(unsigned short s) {
    union { unsigned u; float f; } v; v.u = ((unsigned)s) << 16;
    return v.f;
}
__device__ __forceinline__ float bf2f_s(short s) {
    union { unsigned u; float f; } v; v.u = ((unsigned)(unsigned short)s) << 16;
    return v.f;
}
__device__ __forceinline__ float fsig(float x) {
    float e = __builtin_amdgcn_exp2f(-1.4426950408889634f * x);
    return __builtin_amdgcn_rcpf(1.0f + e);
}
__device__ __forceinline__ float ftanh(float x) {
    float e = __builtin_amdgcn_exp2f(2.8853900817779268f * x);
    return 1.0f - 2.0f * __builtin_amdgcn_rcpf(1.0f + e);
}

// Register discipline (R2-R6 post-mortems), the three hard rules:
//  1. Bf MUST be statically indexed -> FULL unroll of the K-chunk loop.
//  2. No x/bias MFMA in the loop (R5's 202 MB spill); folded into phase B.
//  3. Bound A-frag prefetch depth via memory clobber per chunk (R4/R5 spill).
// Peak live ~122 of the 128 (V+A)/wave cap at 1024 threads (64 VGPR + 64 AGPR
// measured R7). ANY added live register risks per-step scratch.
//
// R7 post-mortem (736us, +15% vs 639.8 baseline): exec-masked A-loads were a
// loss. Conflicts measured 0.0 -> no bank problem existed; the mask added
// per-chunk exec juggling + v_mov zeroing + cndmask into the VALU-busiest
// region (VALUBusy 51%), and WRITE_SIZE 175MB/dispatch (~0.5 dw/thread/step)
// indicates ~2 regs of per-step scratch spill at the 128-reg cliff.
// (WRITE>FETCH asymmetry: spill reads hit L2/L3, spill writes stream to HBM
// -> WRITE_SIZE is the clean spill signal.)
//
// R8 (third submission; two rounds lost to GPU timeout): unconditional
// 64-lane ds_reads restored (identical issue stream to the 639.8us R6
// kernel, -1 live reg), but A-tile is 5 rows: rows 0..3 = h, row 4 =
// permanent zeros. Lanes n>=4 read the SAME row-4 address per q-group ->
// LDS broadcast (no conflict, no serialization). Row 4 is never written:
// phase-B writes max offset 3*SA+255 = 1071 < 4*SA = 1088. Unique bytes per
// chunk read: 1024B -> 320B. Decision variable: WRITE_SIZE. If still
// ~175MB, the baseline itself spills and R9 is a pure register-diet round;
// if ~KB, R9 frees regs then hoists phase-B loop-invariant WxL loads.
__global__ __launch_bounds__(1024)
void ealstm_kernel(const float* __restrict__ x_dyn,  const float* __restrict__ x_stat,
                   const float* __restrict__ W_i,    const float* __restrict__ b_i,
                   const float* __restrict__ W_f,    const float* __restrict__ b_f,
                   const float* __restrict__ W_g,    const float* __restrict__ b_g,
                   const float* __restrict__ W_o,    const float* __restrict__ b_o,
                   const float* __restrict__ W_head, const float* __restrict__ b_head,
                   float* __restrict__ out)
{
    // LDS: 5440 + 12288 + 12288 + 23360 + 432 = 53808 B
    __shared__ __align__(16) unsigned short Abuf[2][AR * SA]; // h rows 0..3 + zero row 4, double-buffered
    __shared__ __align__(16) float          pre[NW * 192];    // h-part preacts, wave-private
    __shared__ __align__(16) unsigned short WxL[G3 * 8];      // per col: Wx[0..4], bias, 0, 0 (bf16)
    __shared__ __align__(16) unsigned short xcA[TS * 4 * 8];  // per (t,row): x[0..4], 1.0, 0, 0 (bf16)
    __shared__ __align__(16) float          xst[BS * NS];

    const int tid  = threadIdx.x;
    const int bid  = blockIdx.x;
    const int b0   = bid * BS;
    const int lane = tid & 63;
    const int wv   = tid >> 6;        // wave 0..15
    const int q    = lane >> 4;       // quad 0..3 (MFMA K-group)
    const int n    = lane & 15;       // MFMA col-in-tile / A row
    const int up   = lane >> 2;       // unit-local 0..15 (phase B)
    const int r    = lane & 3;        // batch row 0..3 (phase B)
    const int u    = wv * UPW + up;   // owned hidden unit (phase B)

    // ---- init LDS ----
    for (int i = tid; i < 2 * AR * SA / 2; i += 1024)
        ((unsigned int*)Abuf)[i] = 0u;                 // zero both A buffers (h0 = 0; row 4 stays 0 forever)
    for (int i = tid; i < BS * NS; i += 1024)
        xst[i] = x_stat[(b0 + i / NS) * NS + (i % NS)];
    for (int i = tid; i < TS * BS; i += 1024) {        // x rows, 16B-aligned per (t,row)
        int t = i >> 2, rr = i & 3;
        const float* xp = x_dyn + ((size_t)(b0 + rr) * TS + t) * DDYN;
        unsigned short* dst = &xcA[(unsigned)i * 8];
        #pragma unroll
        for (int d = 0; d < DDYN; d++) dst[d] = f2bf(xp[d]);
        dst[5] = 0x3F80; dst[6] = 0; dst[7] = 0;
    }
    if (tid < G3) {
        int col = tid;
        int gate = col >> 8, hc = col & 255;
        const float* Wg = gate == 0 ? W_f : (gate == 1 ? W_g : W_o);
        const float* bg = gate == 0 ? b_f : (gate == 1 ? b_g : b_o);
        #pragma unroll
        for (int d = 0; d < DDYN; d++) WxL[col * 8 + d] = f2bf(Wg[hc * (DDYN + HID) + d]);
        WxL[col * 8 + 5] = f2bf(bg[hc]);
        WxL[col * 8 + 6] = 0; WxL[col * 8 + 7] = 0;
    }

    // ---- persistent B fragments: 3 tiles x 8 K-chunks x 4 VGPR = 96 regs ----
    short8 Bf[NTILE][8];
    #pragma unroll
    for (int j = 0; j < NTILE; j++) {
        int urow = wv * UPW + n;           // weight row (hidden unit), gate j
        const float* Wg = j == 0 ? W_f : (j == 1 ? W_g : W_o);
        const float* wrow = Wg + urow * (DDYN + HID) + DDYN;   // skip x-part
        #pragma unroll
        for (int c = 0; c < 8; c++) {
            int k0 = c * 32 + q * 8;
            short8 fr;
            #pragma unroll
            for (int e = 0; e < 8; e++) fr[e] = (short)f2bf(wrow[k0 + e]);
            Bf[j][c] = fr;
        }
    }
    __syncthreads();

    // ---- i_gate for this thread's (unit u, row r) ----
    float ig, cst = 0.f;
    {
        float a = b_i[u];
        for (int s = 0; s < NS; s++)
            a += xst[r * NS + s] * W_i[u * NS + s];
        ig = fsig(a);
    }
    __syncthreads();

    const int aoff  = (n < 4 ? n : 4) * SA;   // rows 4..15 -> shared zero row (LDS broadcast)
    const int pbase = wv * 192 + lane;        // phase-B read base (gate 0)

    // ---- time loop: ONE barrier per step ----
    for (int t = 0; t < TS; t++) {
        const unsigned short* __restrict__ pA = Abuf[t & 1];
        unsigned short*       __restrict__ pB = Abuf[(t + 1) & 1];

        // Phase A: h-part preacts (8 K-chunks, FULLY unrolled -> Bf static).
        f32x4 acc[NTILE];
        #pragma unroll
        for (int j = 0; j < NTILE; j++) acc[j] = (f32x4){0.f, 0.f, 0.f, 0.f};
        #pragma unroll
        for (int c = 0; c < 8; c++) {
            short8 a = *(const short8*)&pA[aoff + c * 32 + q * 8];
            #pragma unroll
            for (int j = 0; j < NTILE; j++)
                acc[j] = __builtin_amdgcn_mfma_f32_16x16x32_bf16(a, Bf[j][c], acc[j], 0, 0, 0);
            // clobber: next chunk's ds_read may not hoist above this point ->
            // at most ~2 A-frags live instead of 8 (R4/R5 spill source).
            __asm__ volatile("" ::: "memory");
        }
        if (q == 0) {   // lanes 0..15 hold rows 0..3 of col n -> wave-private pre region
            #pragma unroll
            for (int j = 0; j < NTILE; j++)
                *(f32x4*)&pre[wv * 192 + j * 64 + n * 4] = acc[j];
        }
        // intra-wave exchange: wave's own writes -> wave's own reads
        __asm__ volatile("s_waitcnt lgkmcnt(0)" ::: "memory");

        // Phase B: LSTM cell for (unit u, row r); x·Wx + bias folded in here
        {
            short8 xv = *(const short8*)&xcA[(unsigned)(t * 4 + r) * 8];
            short8 wf = *(const short8*)&WxL[(u)        * 8];
            short8 wg = *(const short8*)&WxL[(256 + u)  * 8];
            short8 wo = *(const short8*)&WxL[(512 + u)  * 8];
            float pf = pre[pbase]       + bf2f_s(wf[5]);
            float pg = pre[pbase + 64]  + bf2f_s(wg[5]);
            float po = pre[pbase + 128] + bf2f_s(wo[5]);
            #pragma unroll
            for (int d = 0; d < DDYN; d++) {
                float xd = bf2f_s(xv[d]);
                pf += xd * bf2f_s(wf[d]);
                pg += xd * bf2f_s(wg[d]);
                po += xd * bf2f_s(wo[d]);
            }
            float f  = fsig(pf);
            float g_ = ftanh(pg);
            float o  = fsig(po);
            cst = f * cst + ig * g_;
            float h = o * ftanh(cst);
            pB[r * SA + u] = f2bf(h);
        }
        __syncthreads();
    }

    // ---- head: out[b] = h . W_head + b_head (TS odd -> final h in buffer 1) ----
    {
        float h = bf2f(Abuf[1][r * SA + u]);
        pre[u * 4 + r] = h * W_head[u];
    }
    __syncthreads();
    if (tid < 64) {
        f32x4 s = *(const f32x4*)&pre[tid * 4];
        #pragma unroll
        for (int k = 1; k < 4; k++) {
            f32x4 v = *(const f32x4*)&pre[(tid + k * 64) * 4];
            #pragma unroll
            for (int rr = 0; rr < BS; rr++) s[rr] += v[rr];
        }
        #pragma unroll
        for (int off = 32; off > 0; off >>= 1)
            #pragma unroll
            for (int rr = 0; rr < BS; rr++) s[rr] += __shfl_down(s[rr], off, 64);
        if (tid == 0) {
            float bh = b_head[0];
            #pragma unroll
            for (int rr = 0; rr < BS; rr++) out[b0 + rr] = s[rr] + bh;
        }
    }
}

extern "C" void kernel_launch(void* const* d_in, const int* in_sizes, int n_in,
                              void* d_out, int out_size, void* d_ws, size_t ws_size,
                              hipStream_t stream) {
    ealstm_kernel<<<256, 1024, 0, stream>>>(
        (const float*)d_in[0],  (const float*)d_in[1],  (const float*)d_in[2],
        (const float*)d_in[3],  (const float*)d_in[4],  (const float*)d_in[5],
        (const float*)d_in[6],  (const float*)d_in[7],  (const float*)d_in[8],
        (const float*)d_in[9],  (const float*)d_in[10], (const float*)d_in[11],
        (float*)d_out);
}